// Round 17
// baseline (1231.127 us; speedup 1.0000x reference)
//
#include <hip/hip_runtime.h>

constexpr int Cc = 128;   // in_channels (fixed: C=128)
constexpr int NB = 1024;  // bucket table width; bucket = src>>6, needs N <= 65536 (N=50000)
constexpr int CH = 64;    // edge-chunk blocks for hist/scatter passes

// ---------------- per-node dot products: xw1[u] = x[u]·w[0:C] + b, xw2[u] = x[u]·w[C:2C]
__global__ void k_node_dots(const float* __restrict__ x, const float* __restrict__ w,
                            const float* __restrict__ bptr, float* __restrict__ xw1,
                            float* __restrict__ xw2, int N) {
  int wid = (blockIdx.x * blockDim.x + threadIdx.x) >> 6;
  int lane = threadIdx.x & 63;
  if (wid >= N) return;
  const float2* xr = (const float2*)(x + (size_t)wid * Cc);
  const float2* w2 = (const float2*)w;
  float2 v = xr[lane];
  float2 wa = w2[lane];
  float2 wb = w2[lane + 64];
  float s1 = v.x * wa.x + v.y * wa.y;
  float s2 = v.x * wb.x + v.y * wb.y;
#pragma unroll
  for (int off = 32; off >= 1; off >>= 1) {
    s1 += __shfl_xor(s1, off);
    s2 += __shfl_xor(s2, off);
  }
  if (lane == 0) {
    xw1[wid] = s1 + bptr[0];
    xw2[wid] = s2;
  }
}

// ---------------- edge scores + compaction. 1024-thr blocks: 1 hot-counter atomic per
// 1024 edges (~9us serialized total — r12/r15 evidence). Iota folded in.
__global__ void k_edge_score(const int* __restrict__ src, const int* __restrict__ dst,
                             const float* __restrict__ xw1, const float* __restrict__ xw2,
                             float* __restrict__ score, int2* __restrict__ cedge,
                             int* __restrict__ count, int* __restrict__ touched,
                             int* __restrict__ lab, int E, int N) {
  __shared__ int wcnt[16];
  __shared__ int blockbase;
  int e = blockIdx.x * blockDim.x + threadIdx.x;
  int wv = threadIdx.x >> 6, lane = threadIdx.x & 63;
  int s = 0, d = 0;
  bool con = false;
  if (e < E) {
    s = src[e];
    d = dst[e];
    float arg = xw1[s] + xw2[d];  // xw1 already includes bias
    score[e] = tanhf(arg);
    con = arg > 0.0f;  // tanh(arg) > 0 <=> arg > 0 (exact)
    if (con) {
      touched[s] = 1;  // racy same-value stores: benign
      touched[d] = 1;
    }
  }
  if (e < N) lab[e] = e;  // folded iota (E >= N)
  unsigned long long m = __ballot(con);
  int cnt = __popcll(m);
  if (lane == 0) wcnt[wv] = cnt;
  __syncthreads();
  if (threadIdx.x == 0) {
    int tot = 0;
    int pre[16];
#pragma unroll
    for (int j = 0; j < 16; ++j) {
      pre[j] = tot;
      tot += wcnt[j];
    }
    blockbase = tot ? atomicAdd(count, tot) : 0;
#pragma unroll
    for (int j = 0; j < 16; ++j) wcnt[j] = pre[j];
  }
  __syncthreads();
  if (con) {
    int pfx = __popcll(m & ((1ull << lane) - 1ull));
    cedge[blockbase + wcnt[wv] + pfx] = make_int2(s, d);
  }
}

// ---------------- single-pass lock-free union-find CC (ECL-CC style).
// Invariant: lab[v] <= v (parents strictly smaller). Hook larger root under smaller
// root => component min can never be hooked => final root = min node index (exactly
// the reference's fixed point, schedule-independent). Path-halving writes are the
// standard benign races (stale writes still point to valid ancestors).
__device__ __forceinline__ int find_root(int* lab, int v) {
  while (true) {
    int p = lab[v];
    if (p == v) return v;
    int gp = lab[p];
    if (gp != p) lab[v] = gp;  // path halving
    v = gp;
  }
}

__global__ void k_cc_hook(const int2* __restrict__ ce, const int* __restrict__ count,
                          int* __restrict__ lab) {
  int i = blockIdx.x * blockDim.x + threadIdx.x;
  if (i >= *count) return;
  int2 p = ce[i];
  int ru = find_root(lab, p.x);
  int rv = find_root(lab, p.y);
  while (ru != rv) {
    if (ru > rv) {
      int t = ru;
      ru = rv;
      rv = t;
    }
    int old = atomicCAS(&lab[rv], rv, ru);  // hook larger root under smaller
    if (old == rv) break;
    rv = find_root(lab, old);
    ru = find_root(lab, ru);
  }
}

// flatten: read-only walk to root, single store per own index
__global__ void k_cc_flatten(int* __restrict__ lab, int N) {
  int i = blockIdx.x * blockDim.x + threadIdx.x;
  if (i >= N) return;
  int v = i;
  int p = lab[v];
  while (p != v) {
    v = p;
    p = lab[v];
  }
  lab[i] = v;
}

// ---------------- counting sort pass 1: per-chunk bucket histograms (LDS only)
__global__ void k_hist(const int* __restrict__ src, int* __restrict__ T, int E) {
  __shared__ int h[NB];
  for (int i = threadIdx.x; i < NB; i += blockDim.x) h[i] = 0;
  __syncthreads();
  int ch = (E + gridDim.x - 1) / gridDim.x;
  int lo = blockIdx.x * ch, hi = min(lo + ch, E);
  for (int e = lo + threadIdx.x; e < hi; e += blockDim.x) atomicAdd(&h[src[e] >> 6], 1);
  __syncthreads();
  for (int i = threadIdx.x; i < NB; i += blockDim.x) T[blockIdx.x * NB + i] = h[i];
}

// ---------------- pass 2: scan -> per-(chunk,bucket) global bases + bucket ranges bb[]
__global__ void k_scanT(int* __restrict__ T, int* __restrict__ bb, int C, int nb) {
  __shared__ int part[1024];
  int b = threadIdx.x;
  int tot = 0;
  for (int c = 0; c < C; ++c) tot += T[c * NB + b];
  part[b] = tot;
  __syncthreads();
  for (int d = 1; d < 1024; d <<= 1) {
    int v = (b >= d) ? part[b - d] : 0;
    __syncthreads();
    part[b] += v;
    __syncthreads();
  }
  int base = (b == 0) ? 0 : part[b - 1];  // exclusive prefix over buckets
  if (b <= nb) bb[b] = base;              // bb[nb] == E (buckets >= nb are empty)
  int run = base;
  for (int c = 0; c < C; ++c) {
    int v = T[c * NB + b];
    T[c * NB + b] = run;
    run += v;
  }
}

// ---------------- pass 3: scatter edge ids grouped by bucket (LDS cursors, deterministic)
__global__ void k_scat2(const int* __restrict__ src, const int* __restrict__ T,
                        int* __restrict__ pk, int E) {
  __shared__ int cur[NB];
  for (int i = threadIdx.x; i < NB; i += blockDim.x) cur[i] = T[blockIdx.x * NB + i];
  __syncthreads();
  int ch = (E + gridDim.x - 1) / gridDim.x;
  int lo = blockIdx.x * ch, hi = min(lo + ch, E);
  for (int e = lo + threadIdx.x; e < hi; e += blockDim.x) {
    int slot = atomicAdd(&cur[src[e] >> 6], 1);  // LDS atomic
    pk[slot] = e;
  }
}

// ---------------- pass 4: within-bucket sort by node -> pack(dst,score), cnt_src, csr_off
__global__ void k_bucket(const int* __restrict__ pk, const int* __restrict__ bb,
                         const int* __restrict__ src, const int* __restrict__ dst,
                         const float* __restrict__ score, int* __restrict__ cnt_src,
                         int* __restrict__ csr_off, int2* __restrict__ pack, int N) {
  int b = blockIdx.x;
  int lo = bb[b], hi = bb[b + 1];
  __shared__ int h[64], off_s[64], cur[64];
  if (threadIdx.x < 64) h[threadIdx.x] = 0;
  __syncthreads();
  for (int i = lo + threadIdx.x; i < hi; i += blockDim.x) atomicAdd(&h[src[pk[i]] & 63], 1);
  __syncthreads();
  if (threadIdx.x == 0) {
    int run = lo;
    for (int j = 0; j < 64; ++j) {
      off_s[j] = run;
      run += h[j];
    }
  }
  __syncthreads();
  if (threadIdx.x < 64) {
    cur[threadIdx.x] = off_s[threadIdx.x];
    int g = (b << 6) + threadIdx.x;
    if (g < N) {
      csr_off[g] = off_s[threadIdx.x];
      cnt_src[g] = h[threadIdx.x];
    }
  }
  __syncthreads();
  for (int i = lo + threadIdx.x; i < hi; i += blockDim.x) {
    int e = pk[i];
    int slot = atomicAdd(&cur[src[e] & 63], 1);  // LDS atomic
    pack[slot] = make_int2(dst[e], __float_as_int(score[e]));
  }
}

// gather: sx[u] = sum_edges score * x[dst] (+ x[u] if untouched). 2-edge unroll with
// int4 pack loads -> 2x MLP on the pack->x dependent chain (r15/r16).
__global__ void k_sx_csr(const int2* __restrict__ pack, const int* __restrict__ csr_off,
                         const int* __restrict__ cnt_src, const int* __restrict__ touched,
                         const float* __restrict__ x, float* __restrict__ sx, int N) {
  int wid = (blockIdx.x * blockDim.x + threadIdx.x) >> 6;
  int lane = threadIdx.x & 63;
  if (wid >= N) return;
  int beg = csr_off[wid], num = cnt_src[wid];
  float ax = 0.f, ay = 0.f;
  int k = 0;
  if ((beg & 1) && num > 0) {  // align to int4 boundary
    int2 p = pack[beg];
    float t = __int_as_float(p.y);
    float2 v = ((const float2*)(x + (size_t)p.x * Cc))[lane];
    ax += t * v.x;
    ay += t * v.y;
    k = 1;
  }
  for (; k + 1 < num; k += 2) {
    int4 pp = *((const int4*)(pack + beg + k));  // 16B-aligned: beg+k even
    float t0 = __int_as_float(pp.y);
    float t1 = __int_as_float(pp.w);
    float2 v0 = ((const float2*)(x + (size_t)pp.x * Cc))[lane];
    float2 v1 = ((const float2*)(x + (size_t)pp.z * Cc))[lane];
    ax += t0 * v0.x + t1 * v1.x;
    ay += t0 * v0.y + t1 * v1.y;
  }
  if (k < num) {
    int2 p = pack[beg + k];
    float t = __int_as_float(p.y);
    float2 v = ((const float2*)(x + (size_t)p.x * Cc))[lane];
    ax += t * v.x;
    ay += t * v.y;
  }
  if (touched[wid] == 0) {
    float2 v = ((const float2*)(x + (size_t)wid * Cc))[lane];
    ax += v.x;
    ay += v.y;
  }
  ((float2*)(sx + (size_t)wid * Cc))[lane] = make_float2(ax, ay);
}

// x_out[cluster] += sx, run-length compressed. One wave covers all 128 cols (float2);
// CHUNK=128 nodes/wave (r13 fix: hot-row flush atomics 16x fewer).
__global__ void k_segsum(const float* __restrict__ sx, const int* __restrict__ lab,
                         float* __restrict__ xout, int N) {
  const int CHUNK = 128;
  int wv = threadIdx.x >> 6;
  int lane = threadIdx.x & 63;
  int u0 = (blockIdx.x * 4 + wv) * CHUNK;
  if (u0 >= N) return;
  int u1 = min(u0 + CHUNK, N);
  int prevc = lab[u0];
  float ax = 0.f, ay = 0.f;
  for (int u = u0; u < u1; ++u) {
    int c = lab[u];
    float2 v = ((const float2*)(sx + (size_t)u * Cc))[lane];
    if (c != prevc) {
      float* row = xout + (size_t)prevc * Cc + 2 * lane;
      atomicAdd(row, ax);
      atomicAdd(row + 1, ay);
      ax = 0.f;
      ay = 0.f;
      prevc = c;
    }
    ax += v.x;
    ay += v.y;
  }
  float* row = xout + (size_t)prevc * Cc + 2 * lane;
  atomicAdd(row, ax);
  atomicAdd(row + 1, ay);
}

// merged edge + node outputs. Wave-aggregated batch atomicMax.
__global__ void k_outputs(const int* __restrict__ src, const int* __restrict__ dst,
                          const int* __restrict__ lab, const int* __restrict__ batch,
                          float* __restrict__ out_ei, float* __restrict__ out_cluster,
                          float* __restrict__ out_batch, int E, int N) {
  int i = blockIdx.x * blockDim.x + threadIdx.x;
  int lane = threadIdx.x & 63;
  if (i < E) {
    out_ei[i] = (float)lab[src[i]];
    out_ei[E + i] = (float)lab[dst[i]];
  }
  bool valid = i < N;
  int c = valid ? lab[i] : -1;
  float bv = valid ? (float)batch[i] : -1.f;
  if (valid) out_cluster[i] = (float)c;
  unsigned long long remaining = __ballot(valid);
  while (remaining) {
    int leader = __ffsll((unsigned long long)remaining) - 1;
    int lc = __shfl(c, leader);
    bool mine = valid && (c == lc);
    unsigned long long grp = __ballot(mine);
    float v = mine ? bv : -1.f;
#pragma unroll
    for (int off = 32; off >= 1; off >>= 1) v = fmaxf(v, __shfl_xor(v, off));
    if (lane == leader) atomicMax((int*)&out_batch[lc], __float_as_int(v));
    remaining &= ~grp;
  }
}

extern "C" void kernel_launch(void* const* d_in, const int* in_sizes, int n_in,
                              void* d_out, int out_size, void* d_ws, size_t ws_size,
                              hipStream_t stream) {
  const float* x = (const float*)d_in[0];
  const int* ei = (const int*)d_in[1];
  const int* batch = (const int*)d_in[2];
  const float* w = (const float*)d_in[3];
  const float* b = (const float*)d_in[4];
  const int N = in_sizes[2];
  const int E = in_sizes[1] / 2;
  const int* src = ei;
  const int* dst = ei + E;
  const int nb = (N + 63) >> 6;  // buckets; N=50000 -> 782 (<= NB)

  char* ws = (char*)d_ws;
  size_t off = 0;
  auto alloc = [&](size_t bytes) -> void* {
    void* p = ws + off;
    off = (off + bytes + 255) & ~(size_t)255;
    return p;
  };
  int* count = (int*)alloc(256);
  int* touched = (int*)alloc((size_t)N * 4);
  const size_t zero_bytes = off;  // count + touched
  float* xw1 = (float*)alloc((size_t)N * 4);
  float* xw2 = (float*)alloc((size_t)N * 4);
  float* score = (float*)alloc((size_t)E * 4);
  int* lab = (int*)alloc((size_t)N * 4);
  int* cnt_src = (int*)alloc((size_t)N * 4);
  int* csr_off = (int*)alloc((size_t)N * 4);
  int* T = (int*)alloc((size_t)CH * NB * 4);
  int* bb = (int*)alloc((size_t)(NB + 1) * 4);
  int* pk = (int*)alloc((size_t)E * 4);
  int2* pack = (int2*)alloc((size_t)E * 8);
  float* sx = (float*)alloc((size_t)N * Cc * 4);
  int2* cedge = (int2*)sx;  // aliased: cedge dead before k_sx_csr writes sx
  (void)ws_size;            // ~41 MB total; r10 proved >= 43 MB available

  float* out_x = (float*)d_out;
  float* out_ei = out_x + (size_t)N * Cc;
  float* out_batch = out_ei + 2 * (size_t)E;
  float* out_cluster = out_batch + N;

  // zero only accumulated outputs; out_ei/out_cluster fully overwritten by k_outputs
  hipMemsetAsync(out_x, 0, (size_t)N * Cc * 4, stream);
  hipMemsetAsync(out_batch, 0, (size_t)N * 4, stream);
  hipMemsetAsync(d_ws, 0, zero_bytes, stream);

  k_node_dots<<<(N + 3) / 4, 256, 0, stream>>>(x, w, b, xw1, xw2, N);
  k_edge_score<<<(E + 1023) / 1024, 1024, 0, stream>>>(src, dst, xw1, xw2, score, cedge,
                                                       count, touched, lab, E, N);
  // single-pass union-find CC (replaces 10 label-propagation passes: r16 = ~330us -> 2 launches)
  k_cc_hook<<<(E + 255) / 256, 256, 0, stream>>>(cedge, count, lab);
  k_cc_flatten<<<(N + 255) / 256, 256, 0, stream>>>(lab, N);
  // CSR build (no global atomics): hist -> scan -> bucket-scatter -> node-sort
  k_hist<<<CH, 256, 0, stream>>>(src, T, E);
  k_scanT<<<1, 1024, 0, stream>>>(T, bb, CH, nb);
  k_scat2<<<CH, 256, 0, stream>>>(src, T, pk, E);
  k_bucket<<<nb, 256, 0, stream>>>(pk, bb, src, dst, score, cnt_src, csr_off, pack, N);
  // cedge (aliased under sx) is dead from here on
  k_sx_csr<<<(N + 3) / 4, 256, 0, stream>>>(pack, csr_off, cnt_src, touched, x, sx, N);
  k_segsum<<<(N + 511) / 512, 256, 0, stream>>>(sx, lab, out_x, N);
  k_outputs<<<(E + 255) / 256, 256, 0, stream>>>(src, dst, lab, batch, out_ei, out_cluster,
                                                 out_batch, E, N);
}

// Round 18
// 379.294 us; speedup vs baseline: 3.2458x; 3.2458x over previous
//
#include <hip/hip_runtime.h>

constexpr int Cc = 128;   // in_channels (fixed: C=128)
constexpr int NB = 1024;  // bucket table width; bucket = node>>6, needs N <= 65536 (N=50000)
constexpr int CH = 64;    // chunk blocks for hist/scatter passes
constexpr int MAXIT = 12; // CC passes (diameter ~6 at contracted degree ~8; early-exit)

// ---------------- per-node dot products: xw1[u] = x[u]·w[0:C] + b, xw2[u] = x[u]·w[C:2C]
__global__ void k_node_dots(const float* __restrict__ x, const float* __restrict__ w,
                            const float* __restrict__ bptr, float* __restrict__ xw1,
                            float* __restrict__ xw2, int N) {
  int wid = (blockIdx.x * blockDim.x + threadIdx.x) >> 6;
  int lane = threadIdx.x & 63;
  if (wid >= N) return;
  const float2* xr = (const float2*)(x + (size_t)wid * Cc);
  const float2* w2 = (const float2*)w;
  float2 v = xr[lane];
  float2 wa = w2[lane];
  float2 wb = w2[lane + 64];
  float s1 = v.x * wa.x + v.y * wa.y;
  float s2 = v.x * wb.x + v.y * wb.y;
#pragma unroll
  for (int off = 32; off >= 1; off >>= 1) {
    s1 += __shfl_xor(s1, off);
    s2 += __shfl_xor(s2, off);
  }
  if (lane == 0) {
    xw1[wid] = s1 + bptr[0];
    xw2[wid] = s2;
  }
}

// ---------------- edge scores + compaction. 1024-thr blocks: 1 hot-counter atomic per
// 1024 edges (~9us serialized total — r12/r15 evidence). Iota folded in.
__global__ void k_edge_score(const int* __restrict__ src, const int* __restrict__ dst,
                             const float* __restrict__ xw1, const float* __restrict__ xw2,
                             float* __restrict__ score, int2* __restrict__ cedge,
                             int* __restrict__ count, int* __restrict__ touched,
                             int* __restrict__ lab, int E, int N) {
  __shared__ int wcnt[16];
  __shared__ int blockbase;
  int e = blockIdx.x * blockDim.x + threadIdx.x;
  int wv = threadIdx.x >> 6, lane = threadIdx.x & 63;
  int s = 0, d = 0;
  bool con = false;
  if (e < E) {
    s = src[e];
    d = dst[e];
    float arg = xw1[s] + xw2[d];  // xw1 already includes bias
    score[e] = tanhf(arg);
    con = arg > 0.0f;  // tanh(arg) > 0 <=> arg > 0 (exact)
    if (con) {
      touched[s] = 1;  // racy same-value stores: benign
      touched[d] = 1;
    }
  }
  if (e < N) lab[e] = e;  // folded iota (E >= N)
  unsigned long long m = __ballot(con);
  int cnt = __popcll(m);
  if (lane == 0) wcnt[wv] = cnt;
  __syncthreads();
  if (threadIdx.x == 0) {
    int tot = 0;
    int pre[16];
#pragma unroll
    for (int j = 0; j < 16; ++j) {
      pre[j] = tot;
      tot += wcnt[j];
    }
    blockbase = tot ? atomicAdd(count, tot) : 0;
#pragma unroll
    for (int j = 0; j < 16; ++j) wcnt[j] = pre[j];
  }
  __syncthreads();
  if (con) {
    int pfx = __popcll(m & ((1ull << lane) - 1ull));
    cedge[blockbase + wcnt[wv] + pfx] = make_int2(s, d);
  }
}

// ================ bidirectional adjacency CSR of contracted edges (counting sort) ====
// entry i in [0, 2M): node = (i&1)? ce[i/2].y : ce[i/2].x, neighbor = the other.
__global__ void k_hist_adj(const int2* __restrict__ ce, const int* __restrict__ count,
                           int* __restrict__ T) {
  __shared__ int h[NB];
  int M2 = 2 * (*count);
  for (int i = threadIdx.x; i < NB; i += blockDim.x) h[i] = 0;
  __syncthreads();
  int ch = (M2 + gridDim.x - 1) / gridDim.x;
  int lo = blockIdx.x * ch, hi = min(lo + ch, M2);
  for (int i = lo + threadIdx.x; i < hi; i += blockDim.x) {
    int2 p = ce[i >> 1];
    int node = (i & 1) ? p.y : p.x;
    atomicAdd(&h[node >> 6], 1);
  }
  __syncthreads();
  for (int i = threadIdx.x; i < NB; i += blockDim.x) T[blockIdx.x * NB + i] = h[i];
}

// scan: per-(chunk,bucket) global bases + bucket ranges bb[] (shared w/ main build)
__global__ void k_scanT(int* __restrict__ T, int* __restrict__ bb, int C, int nb) {
  __shared__ int part[1024];
  int b = threadIdx.x;
  int tot = 0;
  for (int c = 0; c < C; ++c) tot += T[c * NB + b];
  part[b] = tot;
  __syncthreads();
  for (int d = 1; d < 1024; d <<= 1) {
    int v = (b >= d) ? part[b - d] : 0;
    __syncthreads();
    part[b] += v;
    __syncthreads();
  }
  int base = (b == 0) ? 0 : part[b - 1];
  if (b <= nb) bb[b] = base;
  int run = base;
  for (int c = 0; c < C; ++c) {
    int v = T[c * NB + b];
    T[c * NB + b] = run;
    run += v;
  }
}

__global__ void k_scat_adj(const int2* __restrict__ ce, const int* __restrict__ count,
                           const int* __restrict__ T, int2* __restrict__ apair) {
  __shared__ int cur[NB];
  int M2 = 2 * (*count);
  for (int i = threadIdx.x; i < NB; i += blockDim.x) cur[i] = T[blockIdx.x * NB + i];
  __syncthreads();
  int ch = (M2 + gridDim.x - 1) / gridDim.x;
  int lo = blockIdx.x * ch, hi = min(lo + ch, M2);
  for (int i = lo + threadIdx.x; i < hi; i += blockDim.x) {
    int2 p = ce[i >> 1];
    int node = (i & 1) ? p.y : p.x;
    int nbr = (i & 1) ? p.x : p.y;
    int slot = atomicAdd(&cur[node >> 6], 1);  // LDS atomic
    apair[slot] = make_int2(node, nbr);
  }
}

__global__ void k_bucket_adj(const int2* __restrict__ apair, const int* __restrict__ bb,
                             int* __restrict__ adj_off, int* __restrict__ adj_cnt,
                             int* __restrict__ adj, int N) {
  int b = blockIdx.x;
  int lo = bb[b], hi = bb[b + 1];
  __shared__ int h[64], off_s[64], cur[64];
  if (threadIdx.x < 64) h[threadIdx.x] = 0;
  __syncthreads();
  for (int i = lo + threadIdx.x; i < hi; i += blockDim.x) atomicAdd(&h[apair[i].x & 63], 1);
  __syncthreads();
  if (threadIdx.x == 0) {
    int run = lo;
    for (int j = 0; j < 64; ++j) {
      off_s[j] = run;
      run += h[j];
    }
  }
  __syncthreads();
  if (threadIdx.x < 64) {
    cur[threadIdx.x] = off_s[threadIdx.x];
    int g = (b << 6) + threadIdx.x;
    if (g < N) {
      adj_off[g] = off_s[threadIdx.x];
      adj_cnt[g] = h[threadIdx.x];
    }
  }
  __syncthreads();
  for (int i = lo + threadIdx.x; i < hi; i += blockDim.x) {
    int2 p = apair[i];
    int slot = atomicAdd(&cur[p.x & 63], 1);  // LDS atomic
    adj[slot] = p.y;
  }
}

// ---------------- node-centric Jacobi label propagation: NO atomics (only thread v
// writes lab[v]; racy reads benign under monotone min). Fixed point: labels equal
// across every contracted edge => constant per component => component-min index
// (exactly the reference's fixed point). Early-exit via change flags.
__global__ void k_cc_node(const int* __restrict__ adj_off, const int* __restrict__ adj_cnt,
                          const int* __restrict__ adj, int* __restrict__ lab,
                          int* __restrict__ flags, int it, int N) {
  if (it > 0 && flags[it - 1] == 0) return;  // previous pass was a full no-op
  int v = blockIdx.x * blockDim.x + threadIdx.x;
  if (v >= N) return;
  int a = lab[v];
  int b = lab[a];       // jump 1
  int c = lab[b];       // jump 2
  int m = min(a, min(b, c));
  int beg = adj_off[v], num = adj_cnt[v];
  for (int k = 0; k < num; ++k) m = min(m, lab[adj[beg + k]]);
  if (m < a) {
    lab[v] = m;        // plain store: single writer
    flags[it] = 1;     // racy same-value store: benign
  }
}

// ---------------- main CSR build by src over ALL edges (for sx gather)
__global__ void k_hist(const int* __restrict__ src, int* __restrict__ T, int E) {
  __shared__ int h[NB];
  for (int i = threadIdx.x; i < NB; i += blockDim.x) h[i] = 0;
  __syncthreads();
  int ch = (E + gridDim.x - 1) / gridDim.x;
  int lo = blockIdx.x * ch, hi = min(lo + ch, E);
  for (int e = lo + threadIdx.x; e < hi; e += blockDim.x) atomicAdd(&h[src[e] >> 6], 1);
  __syncthreads();
  for (int i = threadIdx.x; i < NB; i += blockDim.x) T[blockIdx.x * NB + i] = h[i];
}

__global__ void k_scat2(const int* __restrict__ src, const int* __restrict__ T,
                        int* __restrict__ pk, int E) {
  __shared__ int cur[NB];
  for (int i = threadIdx.x; i < NB; i += blockDim.x) cur[i] = T[blockIdx.x * NB + i];
  __syncthreads();
  int ch = (E + gridDim.x - 1) / gridDim.x;
  int lo = blockIdx.x * ch, hi = min(lo + ch, E);
  for (int e = lo + threadIdx.x; e < hi; e += blockDim.x) {
    int slot = atomicAdd(&cur[src[e] >> 6], 1);  // LDS atomic
    pk[slot] = e;
  }
}

__global__ void k_bucket(const int* __restrict__ pk, const int* __restrict__ bb,
                         const int* __restrict__ src, const int* __restrict__ dst,
                         const float* __restrict__ score, int* __restrict__ cnt_src,
                         int* __restrict__ csr_off, int2* __restrict__ pack, int N) {
  int b = blockIdx.x;
  int lo = bb[b], hi = bb[b + 1];
  __shared__ int h[64], off_s[64], cur[64];
  if (threadIdx.x < 64) h[threadIdx.x] = 0;
  __syncthreads();
  for (int i = lo + threadIdx.x; i < hi; i += blockDim.x) atomicAdd(&h[src[pk[i]] & 63], 1);
  __syncthreads();
  if (threadIdx.x == 0) {
    int run = lo;
    for (int j = 0; j < 64; ++j) {
      off_s[j] = run;
      run += h[j];
    }
  }
  __syncthreads();
  if (threadIdx.x < 64) {
    cur[threadIdx.x] = off_s[threadIdx.x];
    int g = (b << 6) + threadIdx.x;
    if (g < N) {
      csr_off[g] = off_s[threadIdx.x];
      cnt_src[g] = h[threadIdx.x];
    }
  }
  __syncthreads();
  for (int i = lo + threadIdx.x; i < hi; i += blockDim.x) {
    int e = pk[i];
    int slot = atomicAdd(&cur[src[e] & 63], 1);  // LDS atomic
    pack[slot] = make_int2(dst[e], __float_as_int(score[e]));
  }
}

// gather: sx[u] = sum_edges score * x[dst] (+ x[u] if untouched). 2-edge unroll with
// int4 pack loads -> 2x MLP on the pack->x dependent chain (r15/r16).
__global__ void k_sx_csr(const int2* __restrict__ pack, const int* __restrict__ csr_off,
                         const int* __restrict__ cnt_src, const int* __restrict__ touched,
                         const float* __restrict__ x, float* __restrict__ sx, int N) {
  int wid = (blockIdx.x * blockDim.x + threadIdx.x) >> 6;
  int lane = threadIdx.x & 63;
  if (wid >= N) return;
  int beg = csr_off[wid], num = cnt_src[wid];
  float ax = 0.f, ay = 0.f;
  int k = 0;
  if ((beg & 1) && num > 0) {  // align to int4 boundary
    int2 p = pack[beg];
    float t = __int_as_float(p.y);
    float2 v = ((const float2*)(x + (size_t)p.x * Cc))[lane];
    ax += t * v.x;
    ay += t * v.y;
    k = 1;
  }
  for (; k + 1 < num; k += 2) {
    int4 pp = *((const int4*)(pack + beg + k));  // 16B-aligned: beg+k even
    float t0 = __int_as_float(pp.y);
    float t1 = __int_as_float(pp.w);
    float2 v0 = ((const float2*)(x + (size_t)pp.x * Cc))[lane];
    float2 v1 = ((const float2*)(x + (size_t)pp.z * Cc))[lane];
    ax += t0 * v0.x + t1 * v1.x;
    ay += t0 * v0.y + t1 * v1.y;
  }
  if (k < num) {
    int2 p = pack[beg + k];
    float t = __int_as_float(p.y);
    float2 v = ((const float2*)(x + (size_t)p.x * Cc))[lane];
    ax += t * v.x;
    ay += t * v.y;
  }
  if (touched[wid] == 0) {
    float2 v = ((const float2*)(x + (size_t)wid * Cc))[lane];
    ax += v.x;
    ay += v.y;
  }
  ((float2*)(sx + (size_t)wid * Cc))[lane] = make_float2(ax, ay);
}

// x_out[cluster] += sx, run-length compressed. One wave covers all 128 cols (float2);
// CHUNK=128 nodes/wave (r13 fix: hot-row flush atomics 16x fewer).
__global__ void k_segsum(const float* __restrict__ sx, const int* __restrict__ lab,
                         float* __restrict__ xout, int N) {
  const int CHUNK = 128;
  int wv = threadIdx.x >> 6;
  int lane = threadIdx.x & 63;
  int u0 = (blockIdx.x * 4 + wv) * CHUNK;
  if (u0 >= N) return;
  int u1 = min(u0 + CHUNK, N);
  int prevc = lab[u0];
  float ax = 0.f, ay = 0.f;
  for (int u = u0; u < u1; ++u) {
    int c = lab[u];
    float2 v = ((const float2*)(sx + (size_t)u * Cc))[lane];
    if (c != prevc) {
      float* row = xout + (size_t)prevc * Cc + 2 * lane;
      atomicAdd(row, ax);
      atomicAdd(row + 1, ay);
      ax = 0.f;
      ay = 0.f;
      prevc = c;
    }
    ax += v.x;
    ay += v.y;
  }
  float* row = xout + (size_t)prevc * Cc + 2 * lane;
  atomicAdd(row, ax);
  atomicAdd(row + 1, ay);
}

// merged edge + node outputs. Wave-aggregated batch atomicMax.
__global__ void k_outputs(const int* __restrict__ src, const int* __restrict__ dst,
                          const int* __restrict__ lab, const int* __restrict__ batch,
                          float* __restrict__ out_ei, float* __restrict__ out_cluster,
                          float* __restrict__ out_batch, int E, int N) {
  int i = blockIdx.x * blockDim.x + threadIdx.x;
  int lane = threadIdx.x & 63;
  if (i < E) {
    out_ei[i] = (float)lab[src[i]];
    out_ei[E + i] = (float)lab[dst[i]];
  }
  bool valid = i < N;
  int c = valid ? lab[i] : -1;
  float bv = valid ? (float)batch[i] : -1.f;
  if (valid) out_cluster[i] = (float)c;
  unsigned long long remaining = __ballot(valid);
  while (remaining) {
    int leader = __ffsll((unsigned long long)remaining) - 1;
    int lc = __shfl(c, leader);
    bool mine = valid && (c == lc);
    unsigned long long grp = __ballot(mine);
    float v = mine ? bv : -1.f;
#pragma unroll
    for (int off = 32; off >= 1; off >>= 1) v = fmaxf(v, __shfl_xor(v, off));
    if (lane == leader) atomicMax((int*)&out_batch[lc], __float_as_int(v));
    remaining &= ~grp;
  }
}

extern "C" void kernel_launch(void* const* d_in, const int* in_sizes, int n_in,
                              void* d_out, int out_size, void* d_ws, size_t ws_size,
                              hipStream_t stream) {
  const float* x = (const float*)d_in[0];
  const int* ei = (const int*)d_in[1];
  const int* batch = (const int*)d_in[2];
  const float* w = (const float*)d_in[3];
  const float* b = (const float*)d_in[4];
  const int N = in_sizes[2];
  const int E = in_sizes[1] / 2;
  const int* src = ei;
  const int* dst = ei + E;
  const int nb = (N + 63) >> 6;  // buckets; N=50000 -> 782 (<= NB)

  char* ws = (char*)d_ws;
  size_t off = 0;
  auto alloc = [&](size_t bytes) -> void* {
    void* p = ws + off;
    off = (off + bytes + 255) & ~(size_t)255;
    return p;
  };
  int* count = (int*)alloc(256);
  int* flags = (int*)alloc((size_t)MAXIT * 4);
  int* touched = (int*)alloc((size_t)N * 4);
  const size_t zero_bytes = off;  // count + flags + touched
  float* xw1 = (float*)alloc((size_t)N * 4);
  float* xw2 = (float*)alloc((size_t)N * 4);
  float* score = (float*)alloc((size_t)E * 4);
  int* lab = (int*)alloc((size_t)N * 4);
  int* cnt_src = (int*)alloc((size_t)N * 4);
  int* csr_off = (int*)alloc((size_t)N * 4);
  int* adj_off = (int*)alloc((size_t)N * 4);
  int* adj_cnt = (int*)alloc((size_t)N * 4);
  int* T = (int*)alloc((size_t)CH * NB * 4);
  int* bb = (int*)alloc((size_t)(NB + 1) * 4);
  int* pk = (int*)alloc((size_t)E * 4);
  int2* pack = (int2*)alloc((size_t)E * 8);
  float* sx = (float*)alloc((size_t)N * Cc * 4);
  // aliased inside the sx region (all dead before k_sx_csr writes sx):
  // cedge [0, E*8) ; apair [E*8, E*8+2E*8) ; adj [3E*8, 3E*8+2E*4)
  // E*8 + 2E*8 + 2E*4 = 32E bytes = 25.6MB = N*Cc*4 exactly at N=50000,E=800000.
  int2* cedge = (int2*)sx;
  int2* apair = (int2*)((char*)sx + (size_t)E * 8);
  int* adj = (int*)((char*)sx + (size_t)E * 24);
  (void)ws_size;  // ~40MB total; r10 proved >= 43 MB available

  float* out_x = (float*)d_out;
  float* out_ei = out_x + (size_t)N * Cc;
  float* out_batch = out_ei + 2 * (size_t)E;
  float* out_cluster = out_batch + N;

  // zero only accumulated outputs; out_ei/out_cluster fully overwritten by k_outputs
  hipMemsetAsync(out_x, 0, (size_t)N * Cc * 4, stream);
  hipMemsetAsync(out_batch, 0, (size_t)N * 4, stream);
  hipMemsetAsync(d_ws, 0, zero_bytes, stream);

  k_node_dots<<<(N + 3) / 4, 256, 0, stream>>>(x, w, b, xw1, xw2, N);
  k_edge_score<<<(E + 1023) / 1024, 1024, 0, stream>>>(src, dst, xw1, xw2, score, cedge,
                                                       count, touched, lab, E, N);
  // adjacency CSR of contracted edges (both directions), LDS counting sort
  k_hist_adj<<<CH, 256, 0, stream>>>(cedge, count, T);
  k_scanT<<<1, 1024, 0, stream>>>(T, bb, CH, nb);
  k_scat_adj<<<CH, 256, 0, stream>>>(cedge, count, T, apair);
  k_bucket_adj<<<nb, 256, 0, stream>>>(apair, bb, adj_off, adj_cnt, adj, N);
  // node-centric atomic-free label propagation (replaces r16's atomicMin passes)
  for (int it = 0; it < MAXIT; ++it) {
    k_cc_node<<<(N + 255) / 256, 256, 0, stream>>>(adj_off, adj_cnt, adj, lab, flags, it, N);
  }
  // main CSR build by src over all edges (T/bb reused after adjacency build)
  k_hist<<<CH, 256, 0, stream>>>(src, T, E);
  k_scanT<<<1, 1024, 0, stream>>>(T, bb, CH, nb);
  k_scat2<<<CH, 256, 0, stream>>>(src, T, pk, E);
  k_bucket<<<nb, 256, 0, stream>>>(pk, bb, src, dst, score, cnt_src, csr_off, pack, N);
  // sx region (cedge/apair/adj) dead from here on
  k_sx_csr<<<(N + 3) / 4, 256, 0, stream>>>(pack, csr_off, cnt_src, touched, x, sx, N);
  k_segsum<<<(N + 511) / 512, 256, 0, stream>>>(sx, lab, out_x, N);
  k_outputs<<<(E + 255) / 256, 256, 0, stream>>>(src, dst, lab, batch, out_ei, out_cluster,
                                                 out_batch, E, N);
}